// Round 1
// baseline (138.979 us; speedup 1.0000x reference)
//
#include <hip/hip_runtime.h>

#define NBATCH 4
#define CDIM 256
#define HWDIM 4096
#define KSPLIT 8
#define KCH (HWDIM / KSPLIT) /* 512 */

// ---------- per-channel sums: s[n*C+c] = sum_p X[n][c][p] ----------
__global__ void k_chansum(const float* __restrict__ X, float* __restrict__ s) {
  int row = blockIdx.x; // n*C + c
  const float4* xp = (const float4*)(X + (size_t)row * HWDIM);
  float acc = 0.f;
  for (int i = threadIdx.x; i < HWDIM / 4; i += 256) {
    float4 v = xp[i];
    acc += v.x + v.y + v.z + v.w;
  }
  __shared__ float red[256];
  red[threadIdx.x] = acc;
  __syncthreads();
  for (int off = 128; off > 0; off >>= 1) {
    if (threadIdx.x < (unsigned)off) red[threadIdx.x] += red[threadIdx.x + off];
    __syncthreads();
  }
  if (threadIdx.x == 0) s[row] = red[0];
}

// ---------- Gram partials: Gpart[ks][n][i][j] = sum_{p in chunk} X[n][i][p] X[n][j][p] ----------
__global__ __launch_bounds__(256) void k_gram(const float* __restrict__ X,
                                              float* __restrict__ Gpart) {
  int ti = blockIdx.x, tj = blockIdx.y;
  int n = blockIdx.z / KSPLIT, ks = blockIdx.z % KSPLIT;
  const float* Xn = X + (size_t)n * CDIM * HWDIM;
  __shared__ __align__(16) float As[32][68]; // [k][i]
  __shared__ __align__(16) float Bs[32][68]; // [k][j]
  int t = threadIdx.x;
  int tx = t & 15, ty = t >> 4;
  int lc = t >> 3;         // 0..31 loader channel
  int lp = (t & 7) * 4;    // 0..28 loader p offset
  float acc[4][4] = {};
  const float* baseA = Xn + (size_t)(ti * 64 + lc) * HWDIM + ks * KCH + lp;
  const float* baseB = Xn + (size_t)(tj * 64 + lc) * HWDIM + ks * KCH + lp;
  for (int k0 = 0; k0 < KCH; k0 += 32) {
    float4 a0 = *(const float4*)(baseA + k0);
    float4 a1 = *(const float4*)(baseA + k0 + (size_t)32 * HWDIM);
    float4 b0 = *(const float4*)(baseB + k0);
    float4 b1 = *(const float4*)(baseB + k0 + (size_t)32 * HWDIM);
    __syncthreads();
    As[lp + 0][lc] = a0.x; As[lp + 1][lc] = a0.y; As[lp + 2][lc] = a0.z; As[lp + 3][lc] = a0.w;
    As[lp + 0][lc + 32] = a1.x; As[lp + 1][lc + 32] = a1.y; As[lp + 2][lc + 32] = a1.z; As[lp + 3][lc + 32] = a1.w;
    Bs[lp + 0][lc] = b0.x; Bs[lp + 1][lc] = b0.y; Bs[lp + 2][lc] = b0.z; Bs[lp + 3][lc] = b0.w;
    Bs[lp + 0][lc + 32] = b1.x; Bs[lp + 1][lc + 32] = b1.y; Bs[lp + 2][lc + 32] = b1.z; Bs[lp + 3][lc + 32] = b1.w;
    __syncthreads();
#pragma unroll
    for (int k = 0; k < 32; ++k) {
      float4 av = *(const float4*)&As[k][ty * 4];
      float4 bv = *(const float4*)&Bs[k][tx * 4];
      float a[4] = {av.x, av.y, av.z, av.w};
      float b[4] = {bv.x, bv.y, bv.z, bv.w};
#pragma unroll
      for (int m = 0; m < 4; ++m)
#pragma unroll
        for (int q = 0; q < 4; ++q) acc[m][q] = fmaf(a[m], b[q], acc[m][q]);
    }
  }
  float* Gp = Gpart + ((size_t)ks * NBATCH + n) * CDIM * CDIM;
  int gi = ti * 64 + ty * 4, gj = tj * 64 + tx * 4;
#pragma unroll
  for (int m = 0; m < 4; ++m) {
    float4 v = make_float4(acc[m][0], acc[m][1], acc[m][2], acc[m][3]);
    *(float4*)(Gp + (size_t)(gi + m) * CDIM + gj) = v;
  }
}

// ---------- reduce K-split partials ----------
__global__ void k_gram_reduce(const float* __restrict__ Gpart, float* __restrict__ G) {
  size_t idx = (size_t)blockIdx.x * 256 + threadIdx.x; // over NB*C*C
  float acc = 0.f;
#pragma unroll
  for (int ks = 0; ks < KSPLIT; ++ks)
    acc += Gpart[(size_t)ks * NBATCH * CDIM * CDIM + idx];
  G[idx] = acc;
}

// ---------- t[n] = W1 s[n], r[n] = W0 s[n] ----------
__global__ void k_matvec(const float* __restrict__ W1, const float* __restrict__ W0,
                         const float* __restrict__ s, float* __restrict__ tvec,
                         float* __restrict__ rvec) {
  int n = blockIdx.x;
  const float* W = (blockIdx.y == 0) ? W1 : W0;
  float* outv = (blockIdx.y == 0) ? tvec : rvec;
  __shared__ float sh[CDIM];
  sh[threadIdx.x] = s[n * CDIM + threadIdx.x];
  __syncthreads();
  int i = threadIdx.x;
  float acc = 0.f;
  for (int k = 0; k < CDIM; ++k) acc += W[i * CDIM + k] * sh[k];
  outv[n * CDIM + i] = acc;
}

// ---------- generic 256x256x256 GEMM: C[n] = alpha * op(A) op(B) (+epilogue) ----------
// a(i,k) = TA ? A[k*C+i] : A[i*C+k];  b(k,j) = TB ? B[j*C+k] : B[k*C+j]
// EPI==1: += e1[n][i]*e2[j] + e3[i]*(e4[n][j] + HW*e2[j])   (M's rank-1 bias terms)
template <int TA, int TB, int EPI>
__global__ __launch_bounds__(256) void k_gemm256(
    const float* __restrict__ A, const float* __restrict__ B, float* __restrict__ Cm,
    size_t strideA, size_t strideB, float alpha, const float* __restrict__ e1,
    const float* __restrict__ e2, const float* __restrict__ e3,
    const float* __restrict__ e4) {
  int ti = blockIdx.x * 32, tj = blockIdx.y * 32;
  int n = blockIdx.z;
  const float* An = A + strideA * n;
  const float* Bn = B + strideB * n;
  __shared__ __align__(16) float As[32][36]; // [k][i]
  __shared__ __align__(16) float Bs[32][36]; // [k][j]
  int t = threadIdx.x;
  int tx = t & 15, ty = t >> 4;
  float acc[2][2] = {};
  for (int k0 = 0; k0 < CDIM; k0 += 32) {
    if (TA) {
      int lk = t >> 3, li = (t & 7) * 4;
      float4 v = *(const float4*)(An + (size_t)(k0 + lk) * CDIM + ti + li);
      *(float4*)&As[lk][li] = v;
    } else {
      int li = t >> 3, lk = (t & 7) * 4;
      float4 v = *(const float4*)(An + (size_t)(ti + li) * CDIM + k0 + lk);
      As[lk + 0][li] = v.x; As[lk + 1][li] = v.y; As[lk + 2][li] = v.z; As[lk + 3][li] = v.w;
    }
    if (TB) {
      int lj = t >> 3, lk = (t & 7) * 4;
      float4 v = *(const float4*)(Bn + (size_t)(tj + lj) * CDIM + k0 + lk);
      Bs[lk + 0][lj] = v.x; Bs[lk + 1][lj] = v.y; Bs[lk + 2][lj] = v.z; Bs[lk + 3][lj] = v.w;
    } else {
      int lk = t >> 3, lj = (t & 7) * 4;
      float4 v = *(const float4*)(Bn + (size_t)(k0 + lk) * CDIM + tj + lj);
      *(float4*)&Bs[lk][lj] = v;
    }
    __syncthreads();
#pragma unroll
    for (int k = 0; k < 32; ++k) {
      float2 a = *(const float2*)&As[k][ty * 2];
      float2 b = *(const float2*)&Bs[k][tx * 2];
      acc[0][0] = fmaf(a.x, b.x, acc[0][0]);
      acc[0][1] = fmaf(a.x, b.y, acc[0][1]);
      acc[1][0] = fmaf(a.y, b.x, acc[1][0]);
      acc[1][1] = fmaf(a.y, b.y, acc[1][1]);
    }
    __syncthreads();
  }
  int gi = ti + ty * 2, gj = tj + tx * 2;
  float* Cn = Cm + (size_t)n * CDIM * CDIM;
#pragma unroll
  for (int m = 0; m < 2; ++m)
#pragma unroll
    for (int q = 0; q < 2; ++q) {
      float v = alpha * acc[m][q];
      if (EPI == 1) {
        float tv = e1[n * CDIM + gi + m];
        float b0v = e2[gj + q];
        float b1v = e3[gi + m];
        float rv = e4[n * CDIM + gj + q];
        v += tv * b0v + b1v * (rv + (float)HWDIM * b0v);
      }
      Cn[(size_t)(gi + m) * CDIM + gj + q] = v;
    }
}

// ---------- cvec[n][o] = (1/HW) * sum_j (sum_d b2[d] M[n][d][j]) W3[o][j] + b3[o] ----------
__global__ void k_cvec(const float* __restrict__ M, const float* __restrict__ b2,
                       const float* __restrict__ W3, const float* __restrict__ b3,
                       float* __restrict__ cvec) {
  int n = blockIdx.x;
  __shared__ float b2s[CDIM];
  __shared__ float mv[CDIM];
  int j = threadIdx.x;
  b2s[j] = b2[j];
  __syncthreads();
  const float* Mn = M + (size_t)n * CDIM * CDIM;
  float acc = 0.f;
  for (int d = 0; d < CDIM; ++d) acc += Mn[(size_t)d * CDIM + j] * b2s[d];
  mv[j] = acc;
  __syncthreads();
  float acc2 = 0.f;
  for (int k = 0; k < CDIM; ++k) acc2 += W3[(size_t)j * CDIM + k] * mv[k];
  cvec[n * CDIM + j] = acc2 * (1.0f / HWDIM) + b3[j];
}

// ---------- final: out[n][o][p] = sum_c Aef[n][c][o] X[n][c][p] + cvec[n][o] ----------
__global__ __launch_bounds__(256) void k_final(const float* __restrict__ X,
                                               const float* __restrict__ Aef,
                                               const float* __restrict__ cvec,
                                               float* __restrict__ out) {
  int tp = blockIdx.x, to = blockIdx.y, n = blockIdx.z;
  __shared__ __align__(16) float As[32][68]; // [c][o]
  __shared__ __align__(16) float Xs[32][68]; // [c][p]
  int t = threadIdx.x, tx = t & 15, ty = t >> 4;
  int lr = t >> 3, l4 = (t & 7) * 4;
  float acc[4][4] = {};
  const float* An = Aef + (size_t)n * CDIM * CDIM;
  const float* Xn = X + (size_t)n * CDIM * HWDIM;
  for (int k0 = 0; k0 < CDIM; k0 += 32) {
    float4 av0 = *(const float4*)(An + (size_t)(k0 + lr) * CDIM + to * 64 + l4);
    float4 av1 = *(const float4*)(An + (size_t)(k0 + lr) * CDIM + to * 64 + l4 + 32);
    float4 xv0 = *(const float4*)(Xn + (size_t)(k0 + lr) * HWDIM + tp * 64 + l4);
    float4 xv1 = *(const float4*)(Xn + (size_t)(k0 + lr) * HWDIM + tp * 64 + l4 + 32);
    __syncthreads();
    *(float4*)&As[lr][l4] = av0;
    *(float4*)&As[lr][l4 + 32] = av1;
    *(float4*)&Xs[lr][l4] = xv0;
    *(float4*)&Xs[lr][l4 + 32] = xv1;
    __syncthreads();
#pragma unroll
    for (int k = 0; k < 32; ++k) {
      float4 av = *(const float4*)&As[k][ty * 4];
      float4 xv = *(const float4*)&Xs[k][tx * 4];
      float a[4] = {av.x, av.y, av.z, av.w};
      float x[4] = {xv.x, xv.y, xv.z, xv.w};
#pragma unroll
      for (int m = 0; m < 4; ++m)
#pragma unroll
        for (int q = 0; q < 4; ++q) acc[m][q] = fmaf(a[m], x[q], acc[m][q]);
    }
  }
  int go = to * 64 + ty * 4, gp = tp * 64 + tx * 4;
  float* On = out + (size_t)n * CDIM * HWDIM;
#pragma unroll
  for (int m = 0; m < 4; ++m) {
    float cb = cvec[n * CDIM + go + m];
    float4 v = make_float4(acc[m][0] + cb, acc[m][1] + cb, acc[m][2] + cb, acc[m][3] + cb);
    *(float4*)(On + (size_t)(go + m) * HWDIM + gp) = v;
  }
}

extern "C" void kernel_launch(void* const* d_in, const int* in_sizes, int n_in,
                              void* d_out, int out_size, void* d_ws, size_t ws_size,
                              hipStream_t stream) {
  const float* X  = (const float*)d_in[0];
  const float* w0 = (const float*)d_in[1];
  const float* b0 = (const float*)d_in[2];
  const float* w1 = (const float*)d_in[3];
  const float* b1 = (const float*)d_in[4];
  const float* w2 = (const float*)d_in[5];
  const float* b2 = (const float*)d_in[6];
  const float* w3 = (const float*)d_in[7];
  const float* b3 = (const float*)d_in[8];
  float* out = (float*)d_out;
  float* ws = (float*)d_ws;

  const size_t CC = (size_t)CDIM * CDIM; // 65536
  float* s    = ws;                       // NB*C          = 1024
  float* tvec = ws + 1024;                // 1024
  float* rvec = ws + 2048;                // 1024
  float* cvec = ws + 3072;                // 1024
  float* G    = ws + 4096;                // NB*CC = 262144
  float* T1   = G + NBATCH * CC;
  float* M    = T1 + NBATCH * CC;
  float* T2   = M + NBATCH * CC;
  float* Aef  = T2 + NBATCH * CC;
  float* Gp   = Aef + NBATCH * CC;        // KSPLIT*NB*CC = 2097152

  k_chansum<<<dim3(NBATCH * CDIM), 256, 0, stream>>>(X, s);
  k_gram<<<dim3(4, 4, NBATCH * KSPLIT), 256, 0, stream>>>(X, Gp);
  k_gram_reduce<<<dim3(NBATCH * CDIM * CDIM / 256), 256, 0, stream>>>(Gp, G);
  k_matvec<<<dim3(NBATCH, 2), 256, 0, stream>>>(w1, w0, s, tvec, rvec);
  // T1 = W1 * G
  k_gemm256<0, 0, 0><<<dim3(8, 8, NBATCH), 256, 0, stream>>>(
      w1, G, T1, 0, CC, 1.f, nullptr, nullptr, nullptr, nullptr);
  // M = T1 * W0^T + t b0^T + b1 r^T + HW b1 b0^T
  k_gemm256<0, 1, 1><<<dim3(8, 8, NBATCH), 256, 0, stream>>>(
      T1, w0, M, CC, 0, 1.f, tvec, b0, b1, rvec);
  // T2 = W2^T * M
  k_gemm256<1, 0, 0><<<dim3(8, 8, NBATCH), 256, 0, stream>>>(
      w2, M, T2, 0, CC, 1.f, nullptr, nullptr, nullptr, nullptr);
  // Aef = T2 * W3^T / HW
  k_gemm256<0, 1, 0><<<dim3(8, 8, NBATCH), 256, 0, stream>>>(
      T2, w3, Aef, CC, 0, 1.0f / HWDIM, nullptr, nullptr, nullptr, nullptr);
  k_cvec<<<dim3(NBATCH), 256, 0, stream>>>(M, b2, w3, b3, cvec);
  k_final<<<dim3(HWDIM / 64, CDIM / 64, NBATCH), 256, 0, stream>>>(X, Aef, cvec, out);
}